// Round 1
// baseline (157.792 us; speedup 1.0000x reference)
//
#include <hip/hip_runtime.h>

typedef __attribute__((ext_vector_type(8))) short short8;
typedef __attribute__((ext_vector_type(4))) float floatx4;
typedef __attribute__((ext_vector_type(4))) float float4v;
typedef __attribute__((ext_vector_type(4))) unsigned short ushort4v;

#define TILE_M 64
#define TILE_SHORTS (TILE_M * 256)   // 16384 shorts = 32 KB per buffer (flat, swizzled)

static __device__ __forceinline__ unsigned short f2bf(float x) {
    unsigned int u = __builtin_bit_cast(unsigned int, x);
    unsigned int r = (u + 0x7FFFu + ((u >> 16) & 1u)) >> 16;
    return (unsigned short)r;
}

// async 16B global -> LDS (DMA, lands at lds_base + lane*16)
static __device__ __forceinline__ void gld16(const unsigned short* g, unsigned short* l) {
    __builtin_amdgcn_global_load_lds(
        (const __attribute__((address_space(1))) unsigned int*)g,
        (__attribute__((address_space(3))) unsigned int*)l, 16, 0, 0);
}

// One prep launch: tables fp32->bf16 (vectorized) + W1 [256k][128n] -> w1t [128n][256k] bf16
__global__ void prep_all(const float* __restrict__ zd, const float* __restrict__ zs,
                         const float* __restrict__ W1,
                         int nd4, int ns4,
                         unsigned short* __restrict__ outd, unsigned short* __restrict__ outs,
                         unsigned short* __restrict__ w1t) {
    int i = blockIdx.x * 256 + threadIdx.x;
    int total4 = nd4 + ns4;
    if (i < total4) {
        const float* src; unsigned short* dst; int j;
        if (i < nd4) { src = zd; dst = outd; j = i; }
        else         { src = zs; dst = outs; j = i - nd4; }
        float4v v = *reinterpret_cast<const float4v*>(src + (size_t)j * 4);
        ushort4v o;
        o.x = f2bf(v.x); o.y = f2bf(v.y); o.z = f2bf(v.z); o.w = f2bf(v.w);
        *reinterpret_cast<ushort4v*>(dst + (size_t)j * 4) = o;
    } else {
        int j = i - total4;
        if (j < 128 * 256) {
            int n = j >> 8;
            int k = j & 255;
            w1t[n * 256 + k] = f2bf(W1[k * 128 + n]);
        }
    }
}

// 8-wave (512-thread) blocks: wave w -> hidden quarter (w>>1)*32, edge half (w&1)*32.
// wfrag = 16 x short8 = 64 VGPRs (vs 128 before) -> unified regfile fits 4 waves/SIMD,
// 2 blocks/CU (LDS-limited) = 16 waves/CU, double the previous occupancy.
//
// LDS tile layout (flat, DMA-compatible, XOR-swizzled): chunk slot c (16B) holds
// edge e = c>>5, physical chunk jx = c&31, storing logical k-chunk j = jx ^ (e&7).
//
// Round r (ONE barrier per round):
//   barrier -> DMA(t+1) -> idx prefetch -> E2 out(t-2) -> E1a fma-reduce(t-1)
//   -> acc init (= b1, folds bias add) -> K-loop MFMA (setprio 1)
//   -> E1b shuffles + red store (t-1)  [runs in MFMA shadow]
__global__ __launch_bounds__(512, 4) void edge_mlp(
    const unsigned short* __restrict__ zd, const unsigned short* __restrict__ zs,
    const int* __restrict__ row, const int* __restrict__ col,
    const unsigned short* __restrict__ w1t,
    const float* __restrict__ b1, const float* __restrict__ w2,
    const float* __restrict__ b2, float* __restrict__ out, int ntiles)
{
    __shared__ unsigned short lds_a[2][TILE_SHORTS];  // 64 KB double buffer
    __shared__ float red[2][4][TILE_M];               // 2 KB, slot = tile_index & 1

    const int tid  = threadIdx.x;
    const int lane = tid & 63;
    const int wave = tid >> 6;           // 0..7
    const int wh   = wave >> 1;          // hidden quarter: [wh*32, wh*32+32)
    const int we   = wave & 1;           // edge half:      [we*32, we*32+32)
    const int l15  = lane & 15;
    const int quad = lane >> 4;
    const int whbase = wh * 32;

    // ---- persistent W1 A-fragments from prepped w1t (64 VGPRs) ----
    // A[m=hidden][k]: m = whbase + mt*16 + l15, k = s*32 + quad*8 + j
    short8 wfrag[16];                    // [s*2 + mt]
    #pragma unroll
    for (int s = 0; s < 8; ++s)
        #pragma unroll
        for (int mt = 0; mt < 2; ++mt)
            wfrag[s * 2 + mt] = *reinterpret_cast<const short8*>(
                &w1t[(size_t)(whbase + mt * 16 + l15) * 256 + s * 32 + quad * 8]);

    // ---- persistent epilogue constants (16 VGPRs) ----
    floatx4 b1v[2], w2v[2];
    #pragma unroll
    for (int mt = 0; mt < 2; ++mt) {
        b1v[mt] = *reinterpret_cast<const floatx4*>(&b1[whbase + mt * 16 + quad * 4]);
        w2v[mt] = *reinterpret_cast<const floatx4*>(&w2[whbase + mt * 16 + quad * 4]);
    }
    const float b2v = b2[0];

    // ---- fixed staging geometry: 4 chunks/thread ----
    const int e0 = tid >> 5;             // 0..15, edges e0 + 16i; (e0+16i)&7 == e0&7
    const int jxw = tid & 31;            // physical chunk this thread fills
    const int jlog = jxw ^ (e0 & 7);     // logical k-chunk it fetches
    const unsigned short* tab = (jlog >= 16) ? zs : zd;
    const int* idxp = (jlog >= 16) ? col : row;
    const int koff = (jlog & 15) * 8;

    // reader swizzle constants
    const int hb = (l15 >> 2) & 1;
    const int qx = quad ^ (l15 & 3);

    const int G = gridDim.x;
    const int R = ntiles / G;            // 16384/512 = 32, uniform
    const long t0 = blockIdx.x;

    // ---- prologue: DMA tile t0 into buf 0; prefetch indices for t0+G ----
    int nidx[4];
    #pragma unroll
    for (int i = 0; i < 4; ++i) nidx[i] = idxp[t0 * TILE_M + e0 + 16 * i];
    #pragma unroll
    for (int i = 0; i < 4; ++i)
        gld16(tab + (size_t)nidx[i] * 128 + koff, &lds_a[0][4096 * i + 512 * wave]);
    {
        long t1 = (R >= 2) ? (t0 + G) : t0;
        #pragma unroll
        for (int i = 0; i < 4; ++i) nidx[i] = idxp[t1 * TILE_M + e0 + 16 * i];
    }

    floatx4 acc[2][2];                   // [et][mt]

    for (int r = 0; r < R; ++r) {
        const long t = t0 + (long)r * G;

        // single barrier: drains DMA(t) into buf[r&1]; syncs red writes of round r-1
        __syncthreads();

        // (a) issue async DMA for tile t+G into the other buffer
        if (r + 1 < R) {
            #pragma unroll
            for (int i = 0; i < 4; ++i)
                gld16(tab + (size_t)nidx[i] * 128 + koff,
                      &lds_a[(r + 1) & 1][4096 * i + 512 * wave]);
        }
        // (b) prefetch indices for tile t+2G
        {
            long t2 = (r + 2 < R) ? (t0 + (long)(r + 2) * G) : t0;
            #pragma unroll
            for (int i = 0; i < 4; ++i) nidx[i] = idxp[t2 * TILE_M + e0 + 16 * i];
        }

        // (c) E2: out-write for tile t-2G (red slot r&1), waves 0..3
        if (r >= 2 && wave < 4 && lane < 16) {
            int eo = wave * 16 + l15;
            out[(t - 2 * G) * TILE_M + eo] =
                red[r & 1][0][eo] + red[r & 1][1][eo] +
                red[r & 1][2][eo] + red[r & 1][3][eo] + b2v;
        }

        // (d) E1a: relu+dot of tile t-G acc (b1 already folded into acc init),
        //     2-way partials to break the fma chain; shuffles deferred to E1b
        float v[2];
        if (r >= 1) {
            #pragma unroll
            for (int et = 0; et < 2; ++et) {
                float p0 = 0.f, p1 = 0.f;
                #pragma unroll
                for (int mt = 0; mt < 2; ++mt)
                    #pragma unroll
                    for (int rr = 0; rr < 4; ++rr) {
                        float h = acc[et][mt][rr];
                        h = h > 0.f ? h : 0.f;
                        if (rr & 1) p1 += h * w2v[mt][rr];
                        else        p0 += h * w2v[mt][rr];
                    }
                v[et] = p0 + p1;
            }
        }

        // (e) acc init = b1 (folds the bias add out of E1)
        #pragma unroll
        for (int et = 0; et < 2; ++et)
            #pragma unroll
            for (int mt = 0; mt < 2; ++mt)
                acc[et][mt] = b1v[mt];

        // (f) K-loop: acc += W1quarter^T x Zhalf on buf[r&1]
        const unsigned short* buf = lds_a[r & 1];
        __builtin_amdgcn_s_setprio(1);
        #pragma unroll
        for (int s = 0; s < 8; ++s) {
            const int sx = s ^ hb;
            short8 ef[2];
            #pragma unroll
            for (int et = 0; et < 2; ++et) {
                int e = we * 32 + et * 16 + l15;
                ef[et] = *reinterpret_cast<const short8*>(&buf[e * 256 + sx * 32 + qx * 8]);
            }
            #pragma unroll
            for (int et = 0; et < 2; ++et)
                #pragma unroll
                for (int mt = 0; mt < 2; ++mt)
                    acc[et][mt] = __builtin_amdgcn_mfma_f32_16x16x32_bf16(
                        wfrag[s * 2 + mt], ef[et], acc[et][mt], 0, 0, 0);
        }
        __builtin_amdgcn_s_setprio(0);

        // (g) E1b: cross-lane reduce + red store for tile t-G (MFMA shadow)
        if (r >= 1) {
            const int slot = (r - 1) & 1;
            #pragma unroll
            for (int et = 0; et < 2; ++et) {
                float x = v[et];
                x += __shfl_xor(x, 16);
                x += __shfl_xor(x, 32);
                if (lane < 16) red[slot][wh][we * 32 + et * 16 + l15] = x;
            }
        }
    }

    // ---- pipeline drain ----
    __syncthreads();                     // syncs red writes of round R-1 (E1 of tile R-2)
    if (R >= 2 && wave < 4 && lane < 16) {   // E2 for tile R-2 (slot R&1 == (R-2)&1)
        int eo = wave * 16 + l15;
        long tt = t0 + (long)(R - 2) * G;
        out[tt * TILE_M + eo] = red[R & 1][0][eo] + red[R & 1][1][eo] +
                                red[R & 1][2][eo] + red[R & 1][3][eo] + b2v;
    }
    {                                    // E1 for tile R-1
        const int slot = (R - 1) & 1;
        #pragma unroll
        for (int et = 0; et < 2; ++et) {
            float p0 = 0.f, p1 = 0.f;
            #pragma unroll
            for (int mt = 0; mt < 2; ++mt)
                #pragma unroll
                for (int rr = 0; rr < 4; ++rr) {
                    float h = acc[et][mt][rr];
                    h = h > 0.f ? h : 0.f;
                    if (rr & 1) p1 += h * w2v[mt][rr];
                    else        p0 += h * w2v[mt][rr];
                }
            float x = p0 + p1;
            x += __shfl_xor(x, 16);
            x += __shfl_xor(x, 32);
            if (lane < 16) red[slot][wh][we * 32 + et * 16 + l15] = x;
        }
    }
    __syncthreads();
    if (wave < 4 && lane < 16) {         // E2 for tile R-1
        int eo = wave * 16 + l15;
        long tt = t0 + (long)(R - 1) * G;
        out[tt * TILE_M + eo] = red[(R - 1) & 1][0][eo] + red[(R - 1) & 1][1][eo] +
                                red[(R - 1) & 1][2][eo] + red[(R - 1) & 1][3][eo] + b2v;
    }
}

extern "C" void kernel_launch(void* const* d_in, const int* in_sizes, int n_in,
                              void* d_out, int out_size, void* d_ws, size_t ws_size,
                              hipStream_t stream) {
    const float* zd = (const float*)d_in[0];
    const float* zs = (const float*)d_in[1];
    const int*   row = (const int*)d_in[2];
    const int*   col = (const int*)d_in[3];
    const float* W1 = (const float*)d_in[4];
    const float* b1 = (const float*)d_in[5];
    const float* w2 = (const float*)d_in[6];
    const float* b2 = (const float*)d_in[7];
    float* out = (float*)d_out;

    const int nd = in_sizes[0];   // 10000*128
    const int ns = in_sizes[1];   // 15000*128
    const int E  = in_sizes[2];   // 1048576

    unsigned short* zd_b = (unsigned short*)d_ws;
    unsigned short* zs_b = zd_b + nd;
    unsigned short* w1t  = zs_b + ns;   // 128*256 bf16

    const int total_jobs = (nd + ns) / 4 + 128 * 256;
    const int pgrid = (total_jobs + 255) / 256;
    hipLaunchKernelGGL(prep_all, dim3(pgrid), dim3(256), 0, stream,
                       zd, zs, W1, nd / 4, ns / 4, zd_b, zs_b, w1t);

    const int ntiles = E / TILE_M;   // 16384
    const int nblocks = 512;         // 2 blocks/CU (LDS-limited), R = 32 rounds
    hipLaunchKernelGGL(edge_mlp, dim3(nblocks), dim3(512), 0, stream,
                       zd_b, zs_b, row, col, w1t, b1, w2, b2, out, ntiles);
}